// Round 10
// baseline (64.564 us; speedup 1.0000x reference)
//
#include <hip/hip_runtime.h>

#define NB 16
#define NL 1024
#define ND 64
#define NW 20
#define CH 8                    // l's per block (rolling)
#define THR 0.3f

typedef float f32x4 __attribute__((ext_vector_type(4)));

// Rolling-window, 256 threads per (b, CH-l chunk); each thread owns a 4x4
// tile. Raw Gram + row/col sum/sumsq in registers; step l->l+1 adds the
// incoming row's outer product and subtracts the outgoing one.
// CH=8/256thr -> 2048 blocks = 8 blocks/CU = 8 waves/SIMD (R7/R9 both had 4
// waves/SIMD and both sat at 62us: store-WAR vmcnt stalls per l-step can't
// be covered by 4 waves; this doubles the cover).
// EPILOGUE MUST keep the reference's denominator eps EXACTLY:
//   corr = cov / (sd_i*sd_j + 1e-8)   (R8: factoring into rsqrt -> absmax 0.7)
// RULES: no runtime indexing into register arrays (R5: scratch demotion, 6x);
// no __launch_bounds__ occupancy hints (R3/R4: forced spill).
__global__ void dyn_corr_kernel(
    const float* __restrict__ x, float* __restrict__ out)
{
    const int blk = blockIdx.x;            // 0..2047
    const int b   = blk >> 7;              // 128 chunks per batch
    const int l0  = (blk & 127) * CH;
    const int t   = threadIdx.x;           // 0..255

    const int NROW = NW - 1 + CH;          // 27 staged rows: l0-19 .. l0+7
    __shared__ float win[NW - 1 + CH][ND]; // 6912 B, raw (uncentered)

    const float* xb = x + ((size_t)b * NL) * ND;

    // --- stage 27 rows (zeros for l<0), f32x4, coalesced ---
    #pragma unroll
    for (int i = 0; i < 2; ++i) {
        int s = t + i * 256;               // valid < 432
        if (s < NROW * 16) {
            int w    = s >> 4;
            int c4   = (s & 15) << 2;
            int lsrc = l0 - (NW - 1) + w;
            f32x4 v = {0.f, 0.f, 0.f, 0.f};
            if (lsrc >= 0) v = *(const f32x4*)&xb[(size_t)lsrc * ND + c4];
            *(f32x4*)&win[w][c4] = v;
        }
    }
    __syncthreads();                       // win read-only from here on

    const int tr = t >> 4;                 // 0..15 -> rows 4*tr..+3
    const int tc = t & 15;                 // 0..15 -> cols 4*tc..+3
    const int d0 = tr << 2;
    const int e0 = tc << 2;

    float acc[4][4] = {};                  // raw Gram tile
    float rs[4] = {}, rq[4] = {};          // row sum / sumsq
    float cs[4] = {}, cq[4] = {};          // col sum / sumsq

    // --- init: full first window, LDS rows 0..19 (= l0-19..l0) ---
    #pragma unroll
    for (int w = 0; w < NW; ++w) {
        f32x4 a0 = *(const f32x4*)&win[w][d0];
        f32x4 b0 = *(const f32x4*)&win[w][e0];
        float ar[4] = {a0.x, a0.y, a0.z, a0.w};
        float br[4] = {b0.x, b0.y, b0.z, b0.w};
        #pragma unroll
        for (int i = 0; i < 4; ++i) {
            rs[i] += ar[i];
            rq[i]  = fmaf(ar[i], ar[i], rq[i]);
            #pragma unroll
            for (int j = 0; j < 4; ++j)
                acc[i][j] = fmaf(ar[i], br[j], acc[i][j]);
        }
        #pragma unroll
        for (int j = 0; j < 4; ++j) {
            cs[j] += br[j];
            cq[j]  = fmaf(br[j], br[j], cq[j]);
        }
    }

    const float invW  = 1.0f / NW;
    const float inv19 = 1.0f / (NW - 1);
    float* obase = out + ((size_t)b * NL + l0) * (ND * ND);

    for (int s = 0; s < CH; ++s) {
        // --- epilogue for l = l0 + s (reference-exact eps semantics) ---
        float sd[4], se[4], mc[4];
        #pragma unroll
        for (int i = 0; i < 4; ++i) {
            float var = fmaf(-rs[i] * invW, rs[i], rq[i]) * inv19;
            sd[i] = sqrtf(var);
        }
        #pragma unroll
        for (int j = 0; j < 4; ++j) {
            mc[j] = cs[j] * invW;
            float var = fmaf(-cs[j], mc[j], cq[j]) * inv19;
            se[j] = sqrtf(var);
        }
        float* ob = obase + (size_t)s * (ND * ND);
        #pragma unroll
        for (int i = 0; i < 4; ++i) {
            f32x4 o;
            float cv;
            cv = fmaf(-rs[i], mc[0], acc[i][0]) * inv19;
            o.x = fmaxf(fabsf(__fdividef(cv, sd[i] * se[0] + 1e-8f)) - THR, 0.0f);
            cv = fmaf(-rs[i], mc[1], acc[i][1]) * inv19;
            o.y = fmaxf(fabsf(__fdividef(cv, sd[i] * se[1] + 1e-8f)) - THR, 0.0f);
            cv = fmaf(-rs[i], mc[2], acc[i][2]) * inv19;
            o.z = fmaxf(fabsf(__fdividef(cv, sd[i] * se[2] + 1e-8f)) - THR, 0.0f);
            cv = fmaf(-rs[i], mc[3], acc[i][3]) * inv19;
            o.w = fmaxf(fabsf(__fdividef(cv, sd[i] * se[3] + 1e-8f)) - THR, 0.0f);
            *(f32x4*)&ob[(d0 + i) * ND + e0] = o;
        }

        // --- rolling update l -> l+1: add LDS row s+20, remove row s ---
        if (s < CH - 1) {
            f32x4 na  = *(const f32x4*)&win[s + NW][d0];
            f32x4 nb  = *(const f32x4*)&win[s + NW][e0];
            f32x4 oa  = *(const f32x4*)&win[s][d0];
            f32x4 obv = *(const f32x4*)&win[s][e0];
            float an[4] = {na.x, na.y, na.z, na.w};
            float bn[4] = {nb.x, nb.y, nb.z, nb.w};
            float ao[4] = {oa.x, oa.y, oa.z, oa.w};
            float bo[4] = {obv.x, obv.y, obv.z, obv.w};
            #pragma unroll
            for (int i = 0; i < 4; ++i) {
                rs[i] += an[i] - ao[i];
                rq[i]  = fmaf(an[i], an[i], fmaf(-ao[i], ao[i], rq[i]));
                #pragma unroll
                for (int j = 0; j < 4; ++j)
                    acc[i][j] = fmaf(an[i], bn[j], fmaf(-ao[i], bo[j], acc[i][j]));
            }
            #pragma unroll
            for (int j = 0; j < 4; ++j) {
                cs[j] += bn[j] - bo[j];
                cq[j]  = fmaf(bn[j], bn[j], fmaf(-bo[j], bo[j], cq[j]));
            }
        }
    }
}

extern "C" void kernel_launch(void* const* d_in, const int* in_sizes, int n_in,
                              void* d_out, int out_size, void* d_ws, size_t ws_size,
                              hipStream_t stream) {
    const float* x = (const float*)d_in[0];
    float* out = (float*)d_out;
    dim3 grid(NB * (NL / CH));
    dim3 block(256);
    hipLaunchKernelGGL(dyn_corr_kernel, grid, block, 0, stream, x, out);
}

// Round 11
// 61.939 us; speedup vs baseline: 1.0424x; 1.0424x over previous
//
#include <hip/hip_runtime.h>

#define NB 16
#define NL 1024
#define ND 64
#define NW 20
#define CH 16                   // l's per block (rolling)
#define THR 0.3f

typedef float f32x4 __attribute__((ext_vector_type(4)));

// Rolling-window, 256 threads per (b, 16-l chunk); each thread owns a 4x4
// tile. Raw Gram + row/col sum/sumsq in registers; step l->l+1 adds the
// incoming row's outer product and subtracts the outgoing one.
// R11: nontemporal stores — output is write-once/never-read; skip L2
// allocation (R9=4 waves, R10=8 waves both ~62-65us => bandwidth-bound on
// the store path at 4.3 TB/s vs fill kernel's 6.9; probe the L2 path).
// EPILOGUE MUST keep the reference's denominator eps EXACTLY:
//   corr = cov / (sd_i*sd_j + 1e-8)   (R8: factoring into rsqrt -> absmax 0.7)
// RULES: no runtime indexing into register arrays (R5: scratch demotion, 6x);
// no __launch_bounds__ occupancy hints (R3/R4: forced spill).
__global__ void dyn_corr_kernel(
    const float* __restrict__ x, float* __restrict__ out)
{
    const int blk = blockIdx.x;            // 0..1023
    const int b   = blk >> 6;              // 64 chunks per batch
    const int l0  = (blk & 63) * CH;
    const int t   = threadIdx.x;           // 0..255

    const int NROW = NW - 1 + CH;          // 35 staged rows: l0-19 .. l0+15
    __shared__ float win[NW - 1 + CH][ND]; // 8960 B, raw (uncentered)

    const float* xb = x + ((size_t)b * NL) * ND;

    // --- stage 35 rows (zeros for l<0), f32x4, coalesced ---
    #pragma unroll
    for (int i = 0; i < 3; ++i) {
        int s = t + i * 256;               // valid < 560
        if (s < NROW * 16) {
            int w    = s >> 4;
            int c4   = (s & 15) << 2;
            int lsrc = l0 - (NW - 1) + w;
            f32x4 v = {0.f, 0.f, 0.f, 0.f};
            if (lsrc >= 0) v = *(const f32x4*)&xb[(size_t)lsrc * ND + c4];
            *(f32x4*)&win[w][c4] = v;
        }
    }
    __syncthreads();                       // win read-only from here on

    const int tr = t >> 4;                 // 0..15 -> rows 4*tr..+3
    const int tc = t & 15;                 // 0..15 -> cols 4*tc..+3
    const int d0 = tr << 2;
    const int e0 = tc << 2;

    float acc[4][4] = {};                  // raw Gram tile
    float rs[4] = {}, rq[4] = {};          // row sum / sumsq
    float cs[4] = {}, cq[4] = {};          // col sum / sumsq

    // --- init: full first window, LDS rows 0..19 (= l0-19..l0) ---
    #pragma unroll
    for (int w = 0; w < NW; ++w) {
        f32x4 a0 = *(const f32x4*)&win[w][d0];
        f32x4 b0 = *(const f32x4*)&win[w][e0];
        float ar[4] = {a0.x, a0.y, a0.z, a0.w};
        float br[4] = {b0.x, b0.y, b0.z, b0.w};
        #pragma unroll
        for (int i = 0; i < 4; ++i) {
            rs[i] += ar[i];
            rq[i]  = fmaf(ar[i], ar[i], rq[i]);
            #pragma unroll
            for (int j = 0; j < 4; ++j)
                acc[i][j] = fmaf(ar[i], br[j], acc[i][j]);
        }
        #pragma unroll
        for (int j = 0; j < 4; ++j) {
            cs[j] += br[j];
            cq[j]  = fmaf(br[j], br[j], cq[j]);
        }
    }

    const float invW  = 1.0f / NW;
    const float inv19 = 1.0f / (NW - 1);
    float* obase = out + ((size_t)b * NL + l0) * (ND * ND);

    for (int s = 0; s < CH; ++s) {
        // --- epilogue for l = l0 + s (reference-exact eps semantics) ---
        float sd[4], se[4], mc[4];
        #pragma unroll
        for (int i = 0; i < 4; ++i) {
            float var = fmaf(-rs[i] * invW, rs[i], rq[i]) * inv19;
            sd[i] = sqrtf(var);
        }
        #pragma unroll
        for (int j = 0; j < 4; ++j) {
            mc[j] = cs[j] * invW;
            float var = fmaf(-cs[j], mc[j], cq[j]) * inv19;
            se[j] = sqrtf(var);
        }
        float* ob = obase + (size_t)s * (ND * ND);
        #pragma unroll
        for (int i = 0; i < 4; ++i) {
            f32x4 o;
            float cv;
            cv = fmaf(-rs[i], mc[0], acc[i][0]) * inv19;
            o.x = fmaxf(fabsf(__fdividef(cv, sd[i] * se[0] + 1e-8f)) - THR, 0.0f);
            cv = fmaf(-rs[i], mc[1], acc[i][1]) * inv19;
            o.y = fmaxf(fabsf(__fdividef(cv, sd[i] * se[1] + 1e-8f)) - THR, 0.0f);
            cv = fmaf(-rs[i], mc[2], acc[i][2]) * inv19;
            o.z = fmaxf(fabsf(__fdividef(cv, sd[i] * se[2] + 1e-8f)) - THR, 0.0f);
            cv = fmaf(-rs[i], mc[3], acc[i][3]) * inv19;
            o.w = fmaxf(fabsf(__fdividef(cv, sd[i] * se[3] + 1e-8f)) - THR, 0.0f);
            __builtin_nontemporal_store(o, (f32x4*)&ob[(d0 + i) * ND + e0]);
        }

        // --- rolling update l -> l+1: add LDS row s+20, remove row s ---
        if (s < CH - 1) {
            f32x4 na  = *(const f32x4*)&win[s + NW][d0];
            f32x4 nb  = *(const f32x4*)&win[s + NW][e0];
            f32x4 oa  = *(const f32x4*)&win[s][d0];
            f32x4 obv = *(const f32x4*)&win[s][e0];
            float an[4] = {na.x, na.y, na.z, na.w};
            float bn[4] = {nb.x, nb.y, nb.z, nb.w};
            float ao[4] = {oa.x, oa.y, oa.z, oa.w};
            float bo[4] = {obv.x, obv.y, obv.z, obv.w};
            #pragma unroll
            for (int i = 0; i < 4; ++i) {
                rs[i] += an[i] - ao[i];
                rq[i]  = fmaf(an[i], an[i], fmaf(-ao[i], ao[i], rq[i]));
                #pragma unroll
                for (int j = 0; j < 4; ++j)
                    acc[i][j] = fmaf(an[i], bn[j], fmaf(-ao[i], bo[j], acc[i][j]));
            }
            #pragma unroll
            for (int j = 0; j < 4; ++j) {
                cs[j] += bn[j] - bo[j];
                cq[j]  = fmaf(bn[j], bn[j], fmaf(-bo[j], bo[j], cq[j]));
            }
        }
    }
}

extern "C" void kernel_launch(void* const* d_in, const int* in_sizes, int n_in,
                              void* d_out, int out_size, void* d_ws, size_t ws_size,
                              hipStream_t stream) {
    const float* x = (const float*)d_in[0];
    float* out = (float*)d_out;
    dim3 grid(NB * (NL / CH));
    dim3 block(256);
    hipLaunchKernelGGL(dyn_corr_kernel, grid, block, 0, stream, x, out);
}

// Round 12
// 61.232 us; speedup vs baseline: 1.0544x; 1.0115x over previous
//
#include <hip/hip_runtime.h>

#define NB 16
#define NL 1024
#define ND 64
#define NW 20
#define CH 16                   // l's per block (rolling)
#define THR 0.3f

typedef float f32x4 __attribute__((ext_vector_type(4)));

// Rolling-window, 256 threads per (b, 16-l chunk). Row ownership is STRIDED:
// thread (q=wave, g=(t>>4)&3, tc=t&15) owns rows {16q + 4i + g, i=0..3} and
// cols 4tc..4tc+3, so store instruction i covers rows 16q+4i..16q+4i+3 ->
// 64 lanes x 16B = 1024B FULLY CONTIGUOUS per VMEM instruction (matches the
// 6.9 TB/s fill kernel's pattern; R9/R11's 4x256B-segmented instructions ran
// at 4.3 TB/s effective).
// EPILOGUE MUST keep the reference's denominator eps EXACTLY:
//   corr = cov / (sd_i*sd_j + 1e-8)   (R8: factoring into rsqrt -> absmax 0.7)
// RULES: no runtime indexing into register arrays (R5: scratch demotion, 6x);
// no __launch_bounds__ occupancy hints (R3/R4: forced spill).
__global__ void dyn_corr_kernel(
    const float* __restrict__ x, float* __restrict__ out)
{
    const int blk = blockIdx.x;            // 0..1023
    const int b   = blk >> 6;              // 64 chunks per batch
    const int l0  = (blk & 63) * CH;
    const int t   = threadIdx.x;           // 0..255

    const int NROW = NW - 1 + CH;          // 35 staged rows: l0-19 .. l0+15
    __shared__ float win[NW - 1 + CH][ND]; // 8960 B, raw (uncentered)

    const float* xb = x + ((size_t)b * NL) * ND;

    // --- stage 35 rows (zeros for l<0), f32x4, coalesced ---
    #pragma unroll
    for (int i = 0; i < 3; ++i) {
        int s = t + i * 256;               // valid < 560
        if (s < NROW * 16) {
            int w    = s >> 4;
            int c4   = (s & 15) << 2;
            int lsrc = l0 - (NW - 1) + w;
            f32x4 v = {0.f, 0.f, 0.f, 0.f};
            if (lsrc >= 0) v = *(const f32x4*)&xb[(size_t)lsrc * ND + c4];
            *(f32x4*)&win[w][c4] = v;
        }
    }
    __syncthreads();                       // win read-only from here on

    const int q  = t >> 6;                 // wave 0..3 -> rows 16q..16q+15
    const int g  = (t >> 4) & 3;           // row-group within wave
    const int tc = t & 15;                 // col group
    const int r0 = (q << 4) + g;           // row(i) = r0 + 4*i
    const int e0 = tc << 2;                // cols e0..e0+3

    float acc[4][4] = {};                  // raw Gram tile (row i, col j)
    float rs[4] = {}, rq[4] = {};          // row sum / sumsq
    float cs[4] = {}, cq[4] = {};          // col sum / sumsq

    // --- init: full first window, LDS rows 0..19 (= l0-19..l0) ---
    #pragma unroll
    for (int w = 0; w < NW; ++w) {
        float ar[4];
        ar[0] = win[w][r0];
        ar[1] = win[w][r0 + 4];
        ar[2] = win[w][r0 + 8];
        ar[3] = win[w][r0 + 12];
        f32x4 b0 = *(const f32x4*)&win[w][e0];
        float br[4] = {b0.x, b0.y, b0.z, b0.w};
        #pragma unroll
        for (int i = 0; i < 4; ++i) {
            rs[i] += ar[i];
            rq[i]  = fmaf(ar[i], ar[i], rq[i]);
            #pragma unroll
            for (int j = 0; j < 4; ++j)
                acc[i][j] = fmaf(ar[i], br[j], acc[i][j]);
        }
        #pragma unroll
        for (int j = 0; j < 4; ++j) {
            cs[j] += br[j];
            cq[j]  = fmaf(br[j], br[j], cq[j]);
        }
    }

    const float invW  = 1.0f / NW;
    const float inv19 = 1.0f / (NW - 1);
    float* obase = out + ((size_t)b * NL + l0) * (ND * ND);

    for (int s = 0; s < CH; ++s) {
        // --- epilogue for l = l0 + s (reference-exact eps semantics) ---
        float sd[4], se[4], mc[4];
        #pragma unroll
        for (int i = 0; i < 4; ++i) {
            float var = fmaf(-rs[i] * invW, rs[i], rq[i]) * inv19;
            sd[i] = sqrtf(var);
        }
        #pragma unroll
        for (int j = 0; j < 4; ++j) {
            mc[j] = cs[j] * invW;
            float var = fmaf(-cs[j], mc[j], cq[j]) * inv19;
            se[j] = sqrtf(var);
        }
        float* ob = obase + (size_t)s * (ND * ND);
        #pragma unroll
        for (int i = 0; i < 4; ++i) {
            f32x4 o;
            float cv;
            cv = fmaf(-rs[i], mc[0], acc[i][0]) * inv19;
            o.x = fmaxf(fabsf(__fdividef(cv, sd[i] * se[0] + 1e-8f)) - THR, 0.0f);
            cv = fmaf(-rs[i], mc[1], acc[i][1]) * inv19;
            o.y = fmaxf(fabsf(__fdividef(cv, sd[i] * se[1] + 1e-8f)) - THR, 0.0f);
            cv = fmaf(-rs[i], mc[2], acc[i][2]) * inv19;
            o.z = fmaxf(fabsf(__fdividef(cv, sd[i] * se[2] + 1e-8f)) - THR, 0.0f);
            cv = fmaf(-rs[i], mc[3], acc[i][3]) * inv19;
            o.w = fmaxf(fabsf(__fdividef(cv, sd[i] * se[3] + 1e-8f)) - THR, 0.0f);
            // instr i: rows 16q+4i+{0..3} x 256B -> 1KB contiguous per wave
            __builtin_nontemporal_store(o, (f32x4*)&ob[(r0 + 4 * i) * ND + e0]);
        }

        // --- rolling update l -> l+1: add LDS row s+20, remove row s ---
        if (s < CH - 1) {
            float an[4], ao[4];
            an[0] = win[s + NW][r0];
            an[1] = win[s + NW][r0 + 4];
            an[2] = win[s + NW][r0 + 8];
            an[3] = win[s + NW][r0 + 12];
            ao[0] = win[s][r0];
            ao[1] = win[s][r0 + 4];
            ao[2] = win[s][r0 + 8];
            ao[3] = win[s][r0 + 12];
            f32x4 nb  = *(const f32x4*)&win[s + NW][e0];
            f32x4 obv = *(const f32x4*)&win[s][e0];
            float bn[4] = {nb.x, nb.y, nb.z, nb.w};
            float bo[4] = {obv.x, obv.y, obv.z, obv.w};
            #pragma unroll
            for (int i = 0; i < 4; ++i) {
                rs[i] += an[i] - ao[i];
                rq[i]  = fmaf(an[i], an[i], fmaf(-ao[i], ao[i], rq[i]));
                #pragma unroll
                for (int j = 0; j < 4; ++j)
                    acc[i][j] = fmaf(an[i], bn[j], fmaf(-ao[i], bo[j], acc[i][j]));
            }
            #pragma unroll
            for (int j = 0; j < 4; ++j) {
                cs[j] += bn[j] - bo[j];
                cq[j]  = fmaf(bn[j], bn[j], fmaf(-bo[j], bo[j], cq[j]));
            }
        }
    }
}

extern "C" void kernel_launch(void* const* d_in, const int* in_sizes, int n_in,
                              void* d_out, int out_size, void* d_ws, size_t ws_size,
                              hipStream_t stream) {
    const float* x = (const float*)d_in[0];
    float* out = (float*)d_out;
    dim3 grid(NB * (NL / CH));
    dim3 block(256);
    hipLaunchKernelGGL(dyn_corr_kernel, grid, block, 0, stream, x, out);
}